// Round 5
// baseline (187.011 us; speedup 1.0000x reference)
//
#include <hip/hip_runtime.h>

typedef __bf16 bf16;
typedef __bf16 bf16x8 __attribute__((ext_vector_type(8)));
typedef __bf16 bf16x4 __attribute__((ext_vector_type(4)));
typedef float  f32x4  __attribute__((ext_vector_type(4)));

#define AS1 __attribute__((address_space(1)))
#define AS3 __attribute__((address_space(3)))

__device__ __forceinline__ void gload16(void* g, void* l) {
  __builtin_amdgcn_global_load_lds((AS1 void*)g, (AS3 void*)l, 16, 0, 0);
}

// ---------------- fused cast fp32 -> bf16 for x + all weights ----------------
__global__ void cast_all(const float4* __restrict__ x,  const float4* __restrict__ wq,
                         const float4* __restrict__ wk, const float4* __restrict__ wv,
                         const float4* __restrict__ wo,
                         bf16x4* __restrict__ xb, bf16x4* __restrict__ wqb,
                         bf16x4* __restrict__ wkvb, bf16x4* __restrict__ wob) {
  long i = (long)blockIdx.x * 256 + threadIdx.x;
  float4 v; bf16x4* dp;
  if (i < 2097152)      { v = x[i];            dp = xb + i; }
  else if (i < 3145728) { v = wq[i - 2097152]; dp = wqb + (i - 2097152); }
  else if (i < 3407872) { v = wk[i - 3145728]; dp = wkvb + (i - 3145728); }
  else if (i < 3670016) { v = wv[i - 3407872]; dp = wkvb + 262144 + (i - 3407872); }
  else                  { v = wo[i - 3670016]; dp = wob + (i - 3670016); }
  bf16x4 o;
  o[0] = (bf16)v.x; o[1] = (bf16)v.y; o[2] = (bf16)v.z; o[3] = (bf16)v.w;
  *dp = o;
}

// =====================================================================
// 8-phase GEMM, BM=256, BN=64*NFR. Deep-pipelined (3 half-tiles in flight):
// ALL fragment ds_reads of a K-tile are front-loaded into its first pre-phase,
// so each LDS buffer frees after phase 1/5 and one half-tile stage issues per
// phase with 4-7 phases of lead. Waits: vmcnt(4+NFR/2) at ph4/ph8 only.
// LDS swizzle: slot ^= (row & 7) (conflict-free, verified r4).
// epi=0: fp32 C.  epi=1: QKV fused epilogue (rope-Q / rope-K / V-transpose).
// =====================================================================
#define PH_OPEN \
  __builtin_amdgcn_s_barrier(); \
  asm volatile("s_waitcnt lgkmcnt(0)" ::: "memory"); \
  __builtin_amdgcn_sched_barrier(0); \
  __builtin_amdgcn_s_setprio(1);

#define PH_CLOSE \
  __builtin_amdgcn_s_setprio(0); \
  __builtin_amdgcn_sched_barrier(0); \
  __builtin_amdgcn_s_barrier();

#define WVM() { if constexpr (NFR == 4) { asm volatile("s_waitcnt vmcnt(6)" ::: "memory"); } \
                else                    { asm volatile("s_waitcnt vmcnt(5)" ::: "memory"); } }

#define MFMAQ(q) \
  _Pragma("unroll") for (int kk = 0; kk < 2; kk++) \
  _Pragma("unroll") for (int m2 = 0; m2 < 2; m2++) \
  _Pragma("unroll") for (int ni = 0; ni < NFR; ni++) \
    acc[(q)*2+m2][ni] = __builtin_amdgcn_mfma_f32_16x16x32_bf16(af[(q)*2+m2][kk], bfr[ni][kk], acc[(q)*2+m2][ni], 0, 0, 0);

template<int NFR>
__global__ __launch_bounds__(512, 2) void gemm8(const bf16* __restrict__ A,
                                                const bf16* __restrict__ Bt,
                                                int N, int epi,
                                                float* __restrict__ Cf,
                                                bf16* __restrict__ qbb,
                                                bf16* __restrict__ kbf,
                                                float* __restrict__ kcache,
                                                float* __restrict__ vcache,
                                                bf16* __restrict__ vtb,
                                                const float* __restrict__ fc,
                                                const float* __restrict__ fs) {
  __shared__ __align__(16) char As[2][32768];
  __shared__ __align__(16) char Bs[2][8192 * NFR];
  const int t = threadIdx.x;
  const int w = t >> 6, l = t & 63, lr = l & 15, lh = l >> 4;
  const int wr = w >> 2, wc = w & 3;
  const int m0 = blockIdx.y << 8, n0 = blockIdx.x * (NFR * 64);

  f32x4 acc[8][NFR];
#pragma unroll
  for (int i = 0; i < 8; i++)
#pragma unroll
    for (int j = 0; j < NFR; j++) acc[i][j] = {0.f, 0.f, 0.f, 0.f};

  // A half-tile = 128 rows x 64 cols bf16 = 16KB = 512thr x 2 x 16B (2 VMEM instr)
  auto stA = [&](int buf, int half, int kt) {
#pragma unroll
    for (int p = 0; p < 2; p++) {
      int c = t + (p << 9);
      int rl = c >> 3, sl = c & 7, gs = sl ^ (rl & 7);
      gload16((void*)(A + (long)(m0 + (half << 7) + rl) * 2048 + (kt << 6) + (gs << 3)),
              &As[buf][(half << 14) + (c << 4)]);
    }
  };
  // B half-tile = (NFR*32) rows x 64 cols (NFR/2 VMEM instr)
  auto stB = [&](int buf, int half, int kt) {
#pragma unroll
    for (int p = 0; p < NFR / 2; p++) {
      int c = t + (p << 9);
      int rl = c >> 3, sl = c & 7, gs = sl ^ (rl & 7);
      gload16((void*)(Bt + (long)(n0 + half * (NFR * 32) + rl) * 2048 + (kt << 6) + (gs << 3)),
              &Bs[buf][half * (NFR * 4096) + (c << 4)]);
    }
  };
  auto rdA = [&](int buf, int mi, int kk) -> bf16x8 {
    int row = (wr << 7) + (mi << 4) + lr;
    int sl  = ((kk << 2) | lh) ^ (row & 7);
    return *(const bf16x8*)(&As[buf][row * 128 + (sl << 4)]);
  };
  auto rdB = [&](int buf, int ni, int kk) -> bf16x8 {
    int row = wc * (NFR * 16) + (ni << 4) + lr;
    int sl  = ((kk << 2) | lh) ^ (row & 7);
    return *(const bf16x8*)(&Bs[buf][row * 128 + (sl << 4)]);
  };

  // ---- prologue: tile0 full (buf0), tile1 A0,A1,B0 (buf1) ----
  stA(0, 0, 0); stA(0, 1, 0); stB(0, 0, 0); stB(0, 1, 0);
  stA(1, 0, 1); stA(1, 1, 1); stB(1, 0, 1);
  WVM();                               // tile0 landed; 3 half-tiles in flight
  __builtin_amdgcn_s_barrier();

  const int NI = 16;   // K=2048 / 128
  for (int j = 0; j < NI; j++) {
    const bool last = (j == NI - 1);
    const int kO = 2 * j + 1;
    bf16x8 af[8][2], bfr[NFR][2];

    // ---- pre-ph1: read ALL of tile E (buf0); stage O.B1 ----
#pragma unroll
    for (int ni = 0; ni < NFR; ni++) { bfr[ni][0] = rdB(0, ni, 0); bfr[ni][1] = rdB(0, ni, 1); }
#pragma unroll
    for (int mi = 0; mi < 8; mi++) { af[mi][0] = rdA(0, mi, 0); af[mi][1] = rdA(0, mi, 1); }
    stB(1, 1, kO);
    PH_OPEN; MFMAQ(0); PH_CLOSE;

    // ---- ph2: stage E'.A0 (buf0.A free since ph1) ----
    if (!last) stA(0, 0, kO + 1);
    PH_OPEN; MFMAQ(1); PH_CLOSE;

    // ---- ph3: stage E'.A1 ----
    if (!last) stA(0, 1, kO + 1);
    PH_OPEN; MFMAQ(2); PH_CLOSE;

    // ---- ph4: stage E'.B0; counted wait -> tile O fully landed ----
    if (!last) stB(0, 0, kO + 1);
    PH_OPEN; MFMAQ(3);
    __builtin_amdgcn_s_setprio(0);
    __builtin_amdgcn_sched_barrier(0);
    if (last) { asm volatile("s_waitcnt vmcnt(0)" ::: "memory"); }
    else      { WVM(); }
    __builtin_amdgcn_s_barrier();

    // ---- pre-ph5: read ALL of tile O (buf1); stage E'.B1 ----
#pragma unroll
    for (int ni = 0; ni < NFR; ni++) { bfr[ni][0] = rdB(1, ni, 0); bfr[ni][1] = rdB(1, ni, 1); }
#pragma unroll
    for (int mi = 0; mi < 8; mi++) { af[mi][0] = rdA(1, mi, 0); af[mi][1] = rdA(1, mi, 1); }
    if (!last) stB(0, 1, kO + 1);
    PH_OPEN; MFMAQ(0); PH_CLOSE;

    // ---- ph6: stage O'.A0 (buf1.A free since ph5) ----
    if (!last) stA(1, 0, kO + 2);
    PH_OPEN; MFMAQ(1); PH_CLOSE;

    // ---- ph7: stage O'.A1 ----
    if (!last) stA(1, 1, kO + 2);
    PH_OPEN; MFMAQ(2); PH_CLOSE;

    // ---- ph8: stage O'.B0; counted wait -> tile E' fully landed ----
    if (!last) stB(1, 0, kO + 2);
    PH_OPEN; MFMAQ(3);
    __builtin_amdgcn_s_setprio(0);
    __builtin_amdgcn_sched_barrier(0);
    if (!last) { WVM(); }
    __builtin_amdgcn_s_barrier();
  }

  // ------------------------- epilogue -------------------------
  if (epi == 0) {
#pragma unroll
    for (int mi = 0; mi < 8; mi++)
#pragma unroll
      for (int ni = 0; ni < NFR; ni++) {
        int col  = n0 + wc * (NFR * 16) + (ni << 4) + lr;
        int rowb = m0 + (wr << 7) + (mi << 4) + (lh << 2);
#pragma unroll
        for (int r = 0; r < 4; r++)
          Cf[(long)(rowb + r) * N + col] = acc[mi][ni][r];
      }
  } else if (n0 < 2048) {          // ---- Q: rope + 1/sqrt(HD), bf16 ----
    const float qs = 0.08838834764831845f;
    const int im = lr & 1;
#pragma unroll
    for (int mi = 0; mi < 8; mi++)
#pragma unroll
      for (int ni = 0; ni < NFR; ni++) {
        int col  = n0 + wc * (NFR * 16) + (ni << 4) + lr;
        int i2   = (col & 127) >> 1;
        int rowb = m0 + (wr << 7) + (mi << 4) + (lh << 2);
#pragma unroll
        for (int r = 0; r < 4; r++) {
          int row = rowb + r, s = row & 1023;
          float c = fc[(s << 6) + i2], sn = fs[(s << 6) + i2];
          float own = acc[mi][ni][r], oth = __shfl_xor(own, 1);
          float xr = im ? oth : own, xi = im ? own : oth;
          float val = im ? (xr * sn + xi * c) : (xr * c - xi * sn);
          qbb[(long)row * 2048 + col] = (bf16)(val * qs);
        }
      }
  } else if (n0 < 2560) {          // ---- K: rope, bf16 + fp32 cache ----
    const int im = lr & 1;
#pragma unroll
    for (int mi = 0; mi < 8; mi++)
#pragma unroll
      for (int ni = 0; ni < NFR; ni++) {
        int col  = n0 + wc * (NFR * 16) + (ni << 4) + lr;
        int ck   = col - 2048;
        int i2   = (ck & 127) >> 1;
        int rowb = m0 + (wr << 7) + (mi << 4) + (lh << 2);
#pragma unroll
        for (int r = 0; r < 4; r++) {
          int row = rowb + r, s = row & 1023;
          float c = fc[(s << 6) + i2], sn = fs[(s << 6) + i2];
          float own = acc[mi][ni][r], oth = __shfl_xor(own, 1);
          float xr = im ? oth : own, xi = im ? own : oth;
          float val = im ? (xr * sn + xi * c) : (xr * c - xi * sn);
          kbf[(long)row * 512 + ck] = (bf16)val;
          kcache[(long)row * 512 + ck] = val;
        }
      }
  } else {                          // ---- V: fp32 cache + transposed bf16 ----
#pragma unroll
    for (int mi = 0; mi < 8; mi++)
#pragma unroll
      for (int ni = 0; ni < NFR; ni++) {
        int col  = n0 + wc * (NFR * 16) + (ni << 4) + lr;
        int cv   = col - 2560;
        int rowb = m0 + (wr << 7) + (mi << 4) + (lh << 2);
        bf16x4 pk;
#pragma unroll
        for (int r = 0; r < 4; r++) {
          float v = acc[mi][ni][r];
          vcache[(long)(rowb + r) * 512 + cv] = v;
          pk[r] = (bf16)v;
        }
        int b = rowb >> 10, s0 = rowb & 1023;
        *(bf16x4*)(vtb + ((long)((b << 2) + (cv >> 7)) * 128 + (cv & 127)) * 1024 + s0) = pk;
      }
  }
}

// ---------------- Flash attention (causal, GQA), double-buffered prefetch -------
__global__ __launch_bounds__(256) void attn_k(const bf16* __restrict__ qb,
                                              const bf16* __restrict__ kb,
                                              const bf16* __restrict__ vt,
                                              bf16* __restrict__ aob) {
  const int bh = blockIdx.x;
  const int qt = 15 - blockIdx.y;       // heavy-first
  const int b = bh >> 4, h = bh & 15, kv = h >> 2;
  const int t = threadIdx.x, w = t >> 6, l = t & 63, lr = l & 15, lh = l >> 4;
  __shared__ __align__(16) char Ks[2][16384];
  __shared__ __align__(16) char Vs[2][16384];
  __shared__ __align__(16) bf16 Ps[4][16][72];

  bf16x8 qfrag[4];
  {
    const int qrow = (qt << 6) + (w << 4) + lr;
    const bf16* qp = qb + ((long)(b * 1024 + qrow) << 11) + (h << 7);
#pragma unroll
    for (int kc = 0; kc < 4; kc++) qfrag[kc] = *(const bf16x8*)(qp + (kc << 5) + (lh << 3));
  }

  f32x4 acc[8];
#pragma unroll
  for (int i = 0; i < 8; i++) acc[i] = {0.f, 0.f, 0.f, 0.f};
  float m[4]  = {-1e30f, -1e30f, -1e30f, -1e30f};
  float ls[4] = {0.f, 0.f, 0.f, 0.f};

  const bf16* kg = kb + ((long)b << 19) + (kv << 7);
  const bf16* vg = vt + ((long)(b * 4 + kv) << 17);
  const int nt = qt + 1;

  auto stage = [&](int buf, int tt2) {
    const int kv0 = tt2 << 6;
#pragma unroll
    for (int pass = 0; pass < 4; pass++) {
      int c = t + (pass << 8);
      { int row = c >> 4, slot = c & 15, gs = slot ^ (row & 7);
        gload16((void*)(kg + (long)(kv0 + row) * 512 + (gs << 3)), &Ks[buf][c * 16]); }
      { int row = c >> 3, slot = c & 7,  gs = slot ^ (row & 7);
        gload16((void*)(vg + (long)row * 1024 + kv0 + (gs << 3)), &Vs[buf][c * 16]); }
    }
  };

  stage(0, 0);
  int cur = 0;

  for (int tt = 0; tt < nt; tt++) {
    __syncthreads();
    if (tt + 1 < nt) stage(cur ^ 1, tt + 1);

    f32x4 s4[4];
#pragma unroll
    for (int nf = 0; nf < 4; nf++) s4[nf] = {0.f, 0.f, 0.f, 0.f};
    __builtin_amdgcn_s_setprio(1);
#pragma unroll
    for (int nf = 0; nf < 4; nf++) {
      int key = (nf << 4) + lr;
#pragma unroll
      for (int kc = 0; kc < 4; kc++) {
        bf16x8 kf8 = *(const bf16x8*)(&Ks[cur][0] + key * 256 + (((kc << 6) + (lh << 4)) ^ ((key & 7) << 4)));
        s4[nf] = __builtin_amdgcn_mfma_f32_16x16x32_bf16(qfrag[kc], kf8, s4[nf], 0, 0, 0);
      }
    }
    __builtin_amdgcn_s_setprio(0);

    if (tt == qt) {
      const int kv0 = tt << 6;
#pragma unroll
      for (int nf = 0; nf < 4; nf++) {
        int key = kv0 + (nf << 4) + lr;
#pragma unroll
        for (int r = 0; r < 4; r++) {
          int qg = (qt << 6) + (w << 4) + (lh << 2) + r;
          if (key > qg) s4[nf][r] = -1e30f;
        }
      }
    }

    float mc[4];
#pragma unroll
    for (int r = 0; r < 4; r++)
      mc[r] = fmaxf(fmaxf(s4[0][r], s4[1][r]), fmaxf(s4[2][r], s4[3][r]));
#pragma unroll
    for (int d = 1; d < 16; d <<= 1)
#pragma unroll
      for (int r = 0; r < 4; r++) mc[r] = fmaxf(mc[r], __shfl_xor(mc[r], d));

    int grow = 0;
#pragma unroll
    for (int r = 0; r < 4; r++) grow |= (mc[r] > m[r] + 8.f) ? 1 : 0;
    if (__any(grow)) {
      f32x4 av;
#pragma unroll
      for (int r = 0; r < 4; r++) {
        float mn = fmaxf(m[r], mc[r]);
        float al = __expf(m[r] - mn);
        m[r] = mn; ls[r] *= al; av[r] = al;
      }
#pragma unroll
      for (int hf = 0; hf < 8; hf++) acc[hf] *= av;
    }

    float rs[4] = {0.f, 0.f, 0.f, 0.f};
#pragma unroll
    for (int nf = 0; nf < 4; nf++)
#pragma unroll
      for (int r = 0; r < 4; r++) {
        float p = __expf(s4[nf][r] - m[r]);
        s4[nf][r] = p;
        rs[r] += p;
      }
#pragma unroll
    for (int d = 1; d < 16; d <<= 1)
#pragma unroll
      for (int r = 0; r < 4; r++) rs[r] += __shfl_xor(rs[r], d);
#pragma unroll
    for (int r = 0; r < 4; r++) ls[r] += rs[r];

#pragma unroll
    for (int nf = 0; nf < 4; nf++)
#pragma unroll
      for (int r = 0; r < 4; r++)
        Ps[w][(lh << 2) + r][(nf << 4) + lr] = (bf16)s4[nf][r];

    __builtin_amdgcn_s_setprio(1);
#pragma unroll
    for (int kc = 0; kc < 2; kc++) {
      bf16x8 pf8 = *(const bf16x8*)((const char*)&Ps[w][lr][0] + (kc << 6) + (lh << 4));
#pragma unroll
      for (int hf = 0; hf < 8; hf++) {
        int hd = (hf << 4) + lr;
        bf16x8 vf8 = *(const bf16x8*)(&Vs[cur][0] + hd * 128 + (((kc << 6) + (lh << 4)) ^ ((hd & 7) << 4)));
        acc[hf] = __builtin_amdgcn_mfma_f32_16x16x32_bf16(pf8, vf8, acc[hf], 0, 0, 0);
      }
    }
    __builtin_amdgcn_s_setprio(0);
    cur ^= 1;
  }

  float inv[4];
#pragma unroll
  for (int r = 0; r < 4; r++) inv[r] = 1.f / ls[r];
#pragma unroll
  for (int hf = 0; hf < 8; hf++)
#pragma unroll
    for (int r = 0; r < 4; r++) {
      int qrow = (qt << 6) + (w << 4) + (lh << 2) + r;
      aob[((long)(b * 1024 + qrow) << 11) + (h << 7) + (hf << 4) + lr] = (bf16)(acc[hf][r] * inv[r]);
    }
}

// ---------------- launch -----------------------------------------
extern "C" void kernel_launch(void* const* d_in, const int* in_sizes, int n_in,
                              void* d_out, int out_size, void* d_ws, size_t ws_size,
                              hipStream_t stream) {
  (void)in_sizes; (void)n_in; (void)out_size; (void)ws_size;
  const float* x  = (const float*)d_in[0];
  const float* fc = (const float*)d_in[1];
  const float* fs = (const float*)d_in[2];
  // d_in[3] = attention_mask: pure causal, implemented directly.
  const float* wq = (const float*)d_in[4];
  const float* wk = (const float*)d_in[5];
  const float* wv = (const float*)d_in[6];
  const float* wo = (const float*)d_in[7];

  float* out    = (float*)d_out;
  float* kcache = out + 8388608;   // (4,1024,4,128)
  float* vcache = out + 10485760;  // (4,1024,4,128)

  char* ws = (char*)d_ws;
  bf16* xb    = (bf16*)(ws);                    // 16 MB
  bf16* wqkv  = (bf16*)(ws + 16777216);         // 12 MB: [wq 8 | wk 2 | wv 2]
  bf16* wob   = (bf16*)(ws + 29360128);         // 8 MB
  bf16* qbb   = (bf16*)(ws + 54525952);         // 16 MB q bf16 (roped, scaled)
  bf16* kbf   = (bf16*)(ws + 71303168);         // 4 MB k bf16 (roped)
  bf16* vtb   = (bf16*)(ws + 75497472);         // 4 MB v^T bf16
  bf16* aob   = (bf16*)(ws + 79691776);         // 16 MB attn out bf16

  cast_all<<<18432, 256, 0, stream>>>((const float4*)x, (const float4*)wq,
                                      (const float4*)wk, (const float4*)wv,
                                      (const float4*)wo,
                                      (bf16x4*)xb, (bf16x4*)wqkv,
                                      (bf16x4*)(wqkv + 4194304), (bf16x4*)wob);

  // fused QKV projection + rope + caches + V-transpose (256x256 tiles)
  gemm8<4><<<dim3(12, 16), 512, 0, stream>>>(xb, wqkv, 3072, 1, nullptr,
                                             qbb, kbf, kcache, vcache, vtb, fc, fs);

  attn_k<<<dim3(64, 16), 256, 0, stream>>>(qbb, kbf, vtb, aob);

  // output projection (256x128 tiles -> 256 blocks, full CU fill)
  gemm8<2><<<dim3(16, 16), 512, 0, stream>>>(aob, wob, 2048, 0, out,
                                             nullptr, nullptr, nullptr, nullptr, nullptr,
                                             nullptr, nullptr);
}

// Round 6
// 171.749 us; speedup vs baseline: 1.0889x; 1.0889x over previous
//
#include <hip/hip_runtime.h>

typedef __bf16 bf16;
typedef __bf16 bf16x8 __attribute__((ext_vector_type(8)));
typedef __bf16 bf16x4 __attribute__((ext_vector_type(4)));
typedef float  f32x4  __attribute__((ext_vector_type(4)));

#define AS1 __attribute__((address_space(1)))
#define AS3 __attribute__((address_space(3)))

__device__ __forceinline__ void gload16(void* g, void* l) {
  __builtin_amdgcn_global_load_lds((AS1 void*)g, (AS3 void*)l, 16, 0, 0);
}

// ---------------- fused cast fp32 -> bf16 for x + all weights ----------------
__global__ void cast_all(const float4* __restrict__ x,  const float4* __restrict__ wq,
                         const float4* __restrict__ wk, const float4* __restrict__ wv,
                         const float4* __restrict__ wo,
                         bf16x4* __restrict__ xb, bf16x4* __restrict__ wqb,
                         bf16x4* __restrict__ wkvb, bf16x4* __restrict__ wob) {
  long i = (long)blockIdx.x * 256 + threadIdx.x;
  float4 v; bf16x4* dp;
  if (i < 2097152)      { v = x[i];            dp = xb + i; }
  else if (i < 3145728) { v = wq[i - 2097152]; dp = wqb + (i - 2097152); }
  else if (i < 3407872) { v = wk[i - 3145728]; dp = wkvb + (i - 3145728); }
  else if (i < 3670016) { v = wv[i - 3407872]; dp = wkvb + 262144 + (i - 3407872); }
  else                  { v = wo[i - 3670016]; dp = wob + (i - 3670016); }
  bf16x4 o;
  o[0] = (bf16)v.x; o[1] = (bf16)v.y; o[2] = (bf16)v.z; o[3] = (bf16)v.w;
  *dp = o;
}

// =====================================================================
// 8-phase GEMM, BM=256, BN=64*NFR (NFR=4 -> 256, 3 -> 192, 2 -> 128).
// r4-proven structure: per-quadrant ds_reads, stages ph1..ph8, counted
// vmcnt at ph4/ph8 only (never 0 in steady state).
// NFR=3: B half-tile = 1.5 passes -> waves 0-3 issue 2 VMEM/stB, waves
// 4-7 issue 1; per-wave-group wait counts (lo vmcnt(4) / hi vmcnt(2)).
// LDS swizzle: slot ^= (row & 7) (conflict-free, verified r4).
// epi=0: fp32 C.  epi=1: per-column QKV epilogue (all fragment columns
// are 16-aligned and Q/K/V boundaries are 16-aligned -> uniform branches).
// =====================================================================
#define PH_OPEN12 \
  asm volatile("s_waitcnt lgkmcnt(8)" ::: "memory"); \
  __builtin_amdgcn_s_barrier(); \
  asm volatile("s_waitcnt lgkmcnt(0)" ::: "memory"); \
  __builtin_amdgcn_sched_barrier(0); \
  __builtin_amdgcn_s_setprio(1);

#define PH_OPEN \
  __builtin_amdgcn_s_barrier(); \
  asm volatile("s_waitcnt lgkmcnt(0)" ::: "memory"); \
  __builtin_amdgcn_sched_barrier(0); \
  __builtin_amdgcn_s_setprio(1);

#define PH_CLOSE \
  __builtin_amdgcn_s_setprio(0); \
  __builtin_amdgcn_sched_barrier(0); \
  __builtin_amdgcn_s_barrier();

// steady-state counted wait: leaves the other tile's B halves in flight
#define WVMT() { \
  if constexpr (NFR == 4) { asm volatile("s_waitcnt vmcnt(4)" ::: "memory"); } \
  else if constexpr (NFR == 3) { \
    if (w < 4) { asm volatile("s_waitcnt vmcnt(4)" ::: "memory"); } \
    else       { asm volatile("s_waitcnt vmcnt(2)" ::: "memory"); } \
  } else { asm volatile("s_waitcnt vmcnt(2)" ::: "memory"); } }

#define MFMAQ(q) \
  _Pragma("unroll") for (int kk = 0; kk < 2; kk++) \
  _Pragma("unroll") for (int m2 = 0; m2 < 2; m2++) \
  _Pragma("unroll") for (int ni = 0; ni < NFR; ni++) \
    acc[(q)*2+m2][ni] = __builtin_amdgcn_mfma_f32_16x16x32_bf16(af[m2][kk], bfr[ni][kk], acc[(q)*2+m2][ni], 0, 0, 0);

template<int NFR>
__global__ __launch_bounds__(512, 2) void gemm8(const bf16* __restrict__ A,
                                                const bf16* __restrict__ Bt,
                                                int N, int epi,
                                                float* __restrict__ Cf,
                                                bf16* __restrict__ qbb,
                                                bf16* __restrict__ kbf,
                                                float* __restrict__ kcache,
                                                float* __restrict__ vcache,
                                                bf16* __restrict__ vtb,
                                                const float* __restrict__ fc,
                                                const float* __restrict__ fs) {
  __shared__ __align__(16) char As[2][32768];
  __shared__ __align__(16) char Bs[2][8192 * NFR];
  const int t = threadIdx.x;
  const int w = t >> 6, l = t & 63, lr = l & 15, lh = l >> 4;
  const int wr = w >> 2, wc = w & 3;
  const int m0 = blockIdx.y << 8, n0 = blockIdx.x * (NFR * 64);

  f32x4 acc[8][NFR];
#pragma unroll
  for (int i = 0; i < 8; i++)
#pragma unroll
    for (int j = 0; j < NFR; j++) acc[i][j] = {0.f, 0.f, 0.f, 0.f};

  // A half-tile = 128 x 64 bf16 = 16KB = 1024 chunks (2 VMEM/thread)
  auto stA = [&](int buf, int half, int kt) {
#pragma unroll
    for (int p = 0; p < 2; p++) {
      int c = t + (p << 9);
      int rl = c >> 3, sl = c & 7, gs = sl ^ (rl & 7);
      gload16((void*)(A + (long)(m0 + (half << 7) + rl) * 2048 + (kt << 6) + (gs << 3)),
              &As[buf][(half << 14) + (c << 4)]);
    }
  };
  // B half-tile = (NFR*32) x 64 = NFR*256 chunks
  auto stB = [&](int buf, int half, int kt) {
    constexpr int CH = NFR * 256;
#pragma unroll
    for (int p = 0; p < (CH + 511) >> 9; p++) {
      int c = t + (p << 9);
      if ((CH & 511) && c >= CH) continue;   // NFR=3: 2nd pass only waves 0-3
      int rl = c >> 3, sl = c & 7, gs = sl ^ (rl & 7);
      gload16((void*)(Bt + (long)(n0 + half * (NFR * 32) + rl) * 2048 + (kt << 6) + (gs << 3)),
              &Bs[buf][half * (NFR * 4096) + (c << 4)]);
    }
  };
  auto rdA = [&](int buf, int mi, int kk) -> bf16x8 {
    int row = (wr << 7) + (mi << 4) + lr;
    int sl  = ((kk << 2) | lh) ^ (row & 7);
    return *(const bf16x8*)(&As[buf][row * 128 + (sl << 4)]);
  };
  auto rdB = [&](int buf, int ni, int kk) -> bf16x8 {
    int row = wc * (NFR * 16) + (ni << 4) + lr;
    int sl  = ((kk << 2) | lh) ^ (row & 7);
    return *(const bf16x8*)(&Bs[buf][row * 128 + (sl << 4)]);
  };

  // ---- prologue: tile0 full (buf0) + tile1.B (buf1) ----
  stB(0, 0, 0); stB(0, 1, 0);
  stA(0, 0, 0); stA(0, 1, 0);
  stB(1, 0, 1); stB(1, 1, 1);
  WVMT();                              // tile0 landed; tile1.B in flight
  __builtin_amdgcn_s_barrier();

  const int NI = 16;   // K=2048 / 128
  for (int j = 0; j < NI; j++) {
    const int ktE = 2 * j, ktO = 2 * j + 1;
    const bool last = (j == NI - 1);
    bf16x8 bfr[NFR][2], af[2][2];

    // ---- phase 1: tile E (buf0) q0; stage O.A0 ----
#pragma unroll
    for (int ni = 0; ni < NFR; ni++) { bfr[ni][0] = rdB(0, ni, 0); bfr[ni][1] = rdB(0, ni, 1); }
    af[0][0] = rdA(0, 0, 0); af[0][1] = rdA(0, 0, 1);
    af[1][0] = rdA(0, 1, 0); af[1][1] = rdA(0, 1, 1);
    stA(1, 0, ktO);
    PH_OPEN12; MFMAQ(0); PH_CLOSE;

    // ---- phase 2: q1; stage O.A1 ----
    af[0][0] = rdA(0, 2, 0); af[0][1] = rdA(0, 2, 1);
    af[1][0] = rdA(0, 3, 0); af[1][1] = rdA(0, 3, 1);
    stA(1, 1, ktO);
    PH_OPEN; MFMAQ(1); PH_CLOSE;

    // ---- phase 3: q2; stage E'.B0 ----
    af[0][0] = rdA(0, 4, 0); af[0][1] = rdA(0, 4, 1);
    af[1][0] = rdA(0, 5, 0); af[1][1] = rdA(0, 5, 1);
    if (!last) stB(0, 0, ktE + 2);
    PH_OPEN; MFMAQ(2); PH_CLOSE;

    // ---- phase 4: q3; stage E'.B1; counted wait -> tile O landed ----
    af[0][0] = rdA(0, 6, 0); af[0][1] = rdA(0, 6, 1);
    af[1][0] = rdA(0, 7, 0); af[1][1] = rdA(0, 7, 1);
    if (!last) stB(0, 1, ktE + 2);
    PH_OPEN; MFMAQ(3);
    __builtin_amdgcn_s_setprio(0);
    __builtin_amdgcn_sched_barrier(0);
    if (last) { asm volatile("s_waitcnt vmcnt(0)" ::: "memory"); }
    else      { WVMT(); }
    __builtin_amdgcn_s_barrier();

    // ---- phase 5: tile O (buf1) q0; stage E'.A0 ----
#pragma unroll
    for (int ni = 0; ni < NFR; ni++) { bfr[ni][0] = rdB(1, ni, 0); bfr[ni][1] = rdB(1, ni, 1); }
    af[0][0] = rdA(1, 0, 0); af[0][1] = rdA(1, 0, 1);
    af[1][0] = rdA(1, 1, 0); af[1][1] = rdA(1, 1, 1);
    if (!last) stA(0, 0, ktE + 2);
    PH_OPEN12; MFMAQ(0); PH_CLOSE;

    // ---- phase 6: q1; stage E'.A1 ----
    af[0][0] = rdA(1, 2, 0); af[0][1] = rdA(1, 2, 1);
    af[1][0] = rdA(1, 3, 0); af[1][1] = rdA(1, 3, 1);
    if (!last) stA(0, 1, ktE + 2);
    PH_OPEN; MFMAQ(1); PH_CLOSE;

    // ---- phase 7: q2; stage O'.B0 ----
    af[0][0] = rdA(1, 4, 0); af[0][1] = rdA(1, 4, 1);
    af[1][0] = rdA(1, 5, 0); af[1][1] = rdA(1, 5, 1);
    if (!last) stB(1, 0, ktO + 2);
    PH_OPEN; MFMAQ(2); PH_CLOSE;

    // ---- phase 8: q3; stage O'.B1; counted wait -> tile E' landed ----
    af[0][0] = rdA(1, 6, 0); af[0][1] = rdA(1, 6, 1);
    af[1][0] = rdA(1, 7, 0); af[1][1] = rdA(1, 7, 1);
    if (!last) stB(1, 1, ktO + 2);
    PH_OPEN; MFMAQ(3);
    __builtin_amdgcn_s_setprio(0);
    __builtin_amdgcn_sched_barrier(0);
    if (!last) { WVMT(); }
    __builtin_amdgcn_s_barrier();
  }

  // ------------------------- epilogue -------------------------
  const float qs = 0.08838834764831845f;  // 1/sqrt(128)
  const int im = lr & 1;
#pragma unroll
  for (int mi = 0; mi < 8; mi++)
#pragma unroll
    for (int ni = 0; ni < NFR; ni++) {
      int col  = n0 + wc * (NFR * 16) + (ni << 4) + lr;
      int rowb = m0 + (wr << 7) + (mi << 4) + (lh << 2);
      if (epi == 0) {
#pragma unroll
        for (int r = 0; r < 4; r++)
          Cf[(long)(rowb + r) * N + col] = acc[mi][ni][r];
      } else if (col < 2048) {          // ---- Q: rope + scale, bf16 ----
        int i2 = (col & 127) >> 1;
#pragma unroll
        for (int r = 0; r < 4; r++) {
          int row = rowb + r, s = row & 1023;
          float c = fc[(s << 6) + i2], sn = fs[(s << 6) + i2];
          float own = acc[mi][ni][r], oth = __shfl_xor(own, 1);
          float xr = im ? oth : own, xi = im ? own : oth;
          float val = im ? (xr * sn + xi * c) : (xr * c - xi * sn);
          qbb[(long)row * 2048 + col] = (bf16)(val * qs);
        }
      } else if (col < 2560) {          // ---- K: rope, bf16 + fp32 cache ----
        int ck = col - 2048;
        int i2 = (ck & 127) >> 1;
#pragma unroll
        for (int r = 0; r < 4; r++) {
          int row = rowb + r, s = row & 1023;
          float c = fc[(s << 6) + i2], sn = fs[(s << 6) + i2];
          float own = acc[mi][ni][r], oth = __shfl_xor(own, 1);
          float xr = im ? oth : own, xi = im ? own : oth;
          float val = im ? (xr * sn + xi * c) : (xr * c - xi * sn);
          kbf[(long)row * 512 + ck] = (bf16)val;
          kcache[(long)row * 512 + ck] = val;
        }
      } else {                          // ---- V: fp32 cache + transposed bf16 ----
        int cv = col - 2560;
        bf16x4 pk;
#pragma unroll
        for (int r = 0; r < 4; r++) {
          float v = acc[mi][ni][r];
          vcache[(long)(rowb + r) * 512 + cv] = v;
          pk[r] = (bf16)v;
        }
        int b = rowb >> 10, s0 = rowb & 1023;
        *(bf16x4*)(vtb + ((long)((b << 2) + (cv >> 7)) * 128 + (cv & 127)) * 1024 + s0) = pk;
      }
    }
}

// ---------------- Flash attention (causal, GQA), double-buffered prefetch -------
__global__ __launch_bounds__(256) void attn_k(const bf16* __restrict__ qb,
                                              const bf16* __restrict__ kb,
                                              const bf16* __restrict__ vt,
                                              bf16* __restrict__ aob) {
  const int bh = blockIdx.x;
  const int qt = 15 - blockIdx.y;       // heavy-first
  const int b = bh >> 4, h = bh & 15, kv = h >> 2;
  const int t = threadIdx.x, w = t >> 6, l = t & 63, lr = l & 15, lh = l >> 4;
  __shared__ __align__(16) char Ks[2][16384];
  __shared__ __align__(16) char Vs[2][16384];
  __shared__ __align__(16) bf16 Ps[4][16][72];

  bf16x8 qfrag[4];
  {
    const int qrow = (qt << 6) + (w << 4) + lr;
    const bf16* qp = qb + ((long)(b * 1024 + qrow) << 11) + (h << 7);
#pragma unroll
    for (int kc = 0; kc < 4; kc++) qfrag[kc] = *(const bf16x8*)(qp + (kc << 5) + (lh << 3));
  }

  f32x4 acc[8];
#pragma unroll
  for (int i = 0; i < 8; i++) acc[i] = {0.f, 0.f, 0.f, 0.f};
  float m[4]  = {-1e30f, -1e30f, -1e30f, -1e30f};
  float ls[4] = {0.f, 0.f, 0.f, 0.f};

  const bf16* kg = kb + ((long)b << 19) + (kv << 7);
  const bf16* vg = vt + ((long)(b * 4 + kv) << 17);
  const int nt = qt + 1;

  auto stage = [&](int buf, int tt2) {
    const int kv0 = tt2 << 6;
#pragma unroll
    for (int pass = 0; pass < 4; pass++) {
      int c = t + (pass << 8);
      { int row = c >> 4, slot = c & 15, gs = slot ^ (row & 7);
        gload16((void*)(kg + (long)(kv0 + row) * 512 + (gs << 3)), &Ks[buf][c * 16]); }
      { int row = c >> 3, slot = c & 7,  gs = slot ^ (row & 7);
        gload16((void*)(vg + (long)row * 1024 + kv0 + (gs << 3)), &Vs[buf][c * 16]); }
    }
  };

  stage(0, 0);
  int cur = 0;

  for (int tt = 0; tt < nt; tt++) {
    __syncthreads();
    if (tt + 1 < nt) stage(cur ^ 1, tt + 1);

    f32x4 s4[4];
#pragma unroll
    for (int nf = 0; nf < 4; nf++) s4[nf] = {0.f, 0.f, 0.f, 0.f};
    __builtin_amdgcn_s_setprio(1);
#pragma unroll
    for (int nf = 0; nf < 4; nf++) {
      int key = (nf << 4) + lr;
#pragma unroll
      for (int kc = 0; kc < 4; kc++) {
        bf16x8 kf8 = *(const bf16x8*)(&Ks[cur][0] + key * 256 + (((kc << 6) + (lh << 4)) ^ ((key & 7) << 4)));
        s4[nf] = __builtin_amdgcn_mfma_f32_16x16x32_bf16(qfrag[kc], kf8, s4[nf], 0, 0, 0);
      }
    }
    __builtin_amdgcn_s_setprio(0);

    if (tt == qt) {
      const int kv0 = tt << 6;
#pragma unroll
      for (int nf = 0; nf < 4; nf++) {
        int key = kv0 + (nf << 4) + lr;
#pragma unroll
        for (int r = 0; r < 4; r++) {
          int qg = (qt << 6) + (w << 4) + (lh << 2) + r;
          if (key > qg) s4[nf][r] = -1e30f;
        }
      }
    }

    float mc[4];
#pragma unroll
    for (int r = 0; r < 4; r++)
      mc[r] = fmaxf(fmaxf(s4[0][r], s4[1][r]), fmaxf(s4[2][r], s4[3][r]));
#pragma unroll
    for (int d = 1; d < 16; d <<= 1)
#pragma unroll
      for (int r = 0; r < 4; r++) mc[r] = fmaxf(mc[r], __shfl_xor(mc[r], d));

    int grow = 0;
#pragma unroll
    for (int r = 0; r < 4; r++) grow |= (mc[r] > m[r] + 8.f) ? 1 : 0;
    if (__any(grow)) {
      f32x4 av;
#pragma unroll
      for (int r = 0; r < 4; r++) {
        float mn = fmaxf(m[r], mc[r]);
        float al = __expf(m[r] - mn);
        m[r] = mn; ls[r] *= al; av[r] = al;
      }
#pragma unroll
      for (int hf = 0; hf < 8; hf++) acc[hf] *= av;
    }

    float rs[4] = {0.f, 0.f, 0.f, 0.f};
#pragma unroll
    for (int nf = 0; nf < 4; nf++)
#pragma unroll
      for (int r = 0; r < 4; r++) {
        float p = __expf(s4[nf][r] - m[r]);
        s4[nf][r] = p;
        rs[r] += p;
      }
#pragma unroll
    for (int d = 1; d < 16; d <<= 1)
#pragma unroll
      for (int r = 0; r < 4; r++) rs[r] += __shfl_xor(rs[r], d);
#pragma unroll
    for (int r = 0; r < 4; r++) ls[r] += rs[r];

#pragma unroll
    for (int nf = 0; nf < 4; nf++)
#pragma unroll
      for (int r = 0; r < 4; r++)
        Ps[w][(lh << 2) + r][(nf << 4) + lr] = (bf16)s4[nf][r];

    __builtin_amdgcn_s_setprio(1);
#pragma unroll
    for (int kc = 0; kc < 2; kc++) {
      bf16x8 pf8 = *(const bf16x8*)((const char*)&Ps[w][lr][0] + (kc << 6) + (lh << 4));
#pragma unroll
      for (int hf = 0; hf < 8; hf++) {
        int hd = (hf << 4) + lr;
        bf16x8 vf8 = *(const bf16x8*)(&Vs[cur][0] + hd * 128 + (((kc << 6) + (lh << 4)) ^ ((hd & 7) << 4)));
        acc[hf] = __builtin_amdgcn_mfma_f32_16x16x32_bf16(pf8, vf8, acc[hf], 0, 0, 0);
      }
    }
    __builtin_amdgcn_s_setprio(0);
    cur ^= 1;
  }

  float inv[4];
#pragma unroll
  for (int r = 0; r < 4; r++) inv[r] = 1.f / ls[r];
#pragma unroll
  for (int hf = 0; hf < 8; hf++)
#pragma unroll
    for (int r = 0; r < 4; r++) {
      int qrow = (qt << 6) + (w << 4) + (lh << 2) + r;
      aob[((long)(b * 1024 + qrow) << 11) + (h << 7) + (hf << 4) + lr] = (bf16)(acc[hf][r] * inv[r]);
    }
}

// ---------------- launch -----------------------------------------
extern "C" void kernel_launch(void* const* d_in, const int* in_sizes, int n_in,
                              void* d_out, int out_size, void* d_ws, size_t ws_size,
                              hipStream_t stream) {
  (void)in_sizes; (void)n_in; (void)out_size; (void)ws_size;
  const float* x  = (const float*)d_in[0];
  const float* fc = (const float*)d_in[1];
  const float* fs = (const float*)d_in[2];
  // d_in[3] = attention_mask: pure causal, implemented directly.
  const float* wq = (const float*)d_in[4];
  const float* wk = (const float*)d_in[5];
  const float* wv = (const float*)d_in[6];
  const float* wo = (const float*)d_in[7];

  float* out    = (float*)d_out;
  float* kcache = out + 8388608;   // (4,1024,4,128)
  float* vcache = out + 10485760;  // (4,1024,4,128)

  char* ws = (char*)d_ws;
  bf16* xb    = (bf16*)(ws);                    // 16 MB
  bf16* wqkv  = (bf16*)(ws + 16777216);         // 12 MB: [wq 8 | wk 2 | wv 2]
  bf16* wob   = (bf16*)(ws + 29360128);         // 8 MB
  bf16* qbb   = (bf16*)(ws + 54525952);         // 16 MB q bf16 (roped, scaled)
  bf16* kbf   = (bf16*)(ws + 71303168);         // 4 MB k bf16 (roped)
  bf16* vtb   = (bf16*)(ws + 75497472);         // 4 MB v^T bf16
  bf16* aob   = (bf16*)(ws + 79691776);         // 16 MB attn out bf16

  cast_all<<<18432, 256, 0, stream>>>((const float4*)x, (const float4*)wq,
                                      (const float4*)wk, (const float4*)wv,
                                      (const float4*)wo,
                                      (bf16x4*)xb, (bf16x4*)wqkv,
                                      (bf16x4*)(wqkv + 4194304), (bf16x4*)wob);

  // fused QKV projection + rope + caches + V-transpose (256x192 tiles, 256 blocks)
  gemm8<3><<<dim3(16, 16), 512, 0, stream>>>(xb, wqkv, 3072, 1, nullptr,
                                             qbb, kbf, kcache, vcache, vtb, fc, fs);

  attn_k<<<dim3(64, 16), 256, 0, stream>>>(qbb, kbf, vtb, aob);

  // output projection (256x128 tiles -> 256 blocks, full CU fill)
  gemm8<2><<<dim3(16, 16), 512, 0, stream>>>(aob, wob, 2048, 0, out,
                                             nullptr, nullptr, nullptr, nullptr, nullptr,
                                             nullptr, nullptr);
}